// Round 7
// baseline (1700.537 us; speedup 1.0000x reference)
//
#include <hip/hip_runtime.h>
#include <stdint.h>

typedef int v4i __attribute__((ext_vector_type(4)));
typedef int v8i __attribute__((ext_vector_type(8)));
typedef float v4f __attribute__((ext_vector_type(4)));
typedef short v8s __attribute__((ext_vector_type(8)));
typedef unsigned long long ull;
typedef unsigned int uint;

#define GLOAD16(g, l)                                                          \
  __builtin_amdgcn_global_load_lds(                                            \
      (const __attribute__((address_space(1))) void*)(g),                      \
      (__attribute__((address_space(3))) void*)(l), 16, 0, 0)

__device__ __forceinline__ void bar() {
  asm volatile("" ::: "memory");
  __builtin_amdgcn_s_barrier();
  asm volatile("" ::: "memory");
}

__device__ __forceinline__ signed char sgnf(float v) {
  return v > 0.f ? (signed char)1 : (v < 0.f ? (signed char)-1 : (signed char)0);
}
// fp4 e2m1 codes: +1.0 = 0x2, -1.0 = 0xA, 0.0 = 0x0
__device__ __forceinline__ uint nib(float v) {
  return v > 0.f ? 2u : (v < 0.f ? 10u : 0u);
}

// ---------------- binarize fp32 -> i8 sign (tiny weights only) ----------------
__global__ void k_bin(const float4* __restrict__ in, char4* __restrict__ out, int n4) {
  int i = blockIdx.x * blockDim.x + threadIdx.x;
  int stride = gridDim.x * blockDim.x;
  for (; i < n4; i += stride) {
    float4 v = in[i];
    char4 o;
    o.x = sgnf(v.x); o.y = sgnf(v.y); o.z = sgnf(v.z); o.w = sgnf(v.w);
    out[i] = o;
  }
}

// ---------------- binarize fp32 -> packed fp4 (2 elems/byte) ----------------
__global__ void k_binp(const float4* __restrict__ in, uint* __restrict__ out, int n8) {
  int i = blockIdx.x * blockDim.x + threadIdx.x;
  int stride = gridDim.x * blockDim.x;
  for (; i < n8; i += stride) {
    float4 a = in[i * 2], b = in[i * 2 + 1];
    out[i] = nib(a.x) | (nib(a.y) << 4) | (nib(a.z) << 8) | (nib(a.w) << 12) |
             (nib(b.x) << 16) | (nib(b.y) << 20) | (nib(b.z) << 24) | (nib(b.w) << 28);
  }
}

// ============ 256x256 4-phase counted-vmcnt MX-fp4 GEMM (T3+T4+T5) ============
// 512 threads = 8 waves (2M x 4N); per-wave C: 128x64. LDS 2 bufs x (A 32K + B 32K).
// Per K-tile (256 elems = 128 B/row): 4 phases x 16 MFMA. Staging ledger (verified
// by construction): ph1 stages A1(t+1)->otherbuf, ph2 B1(t+1)->otherbuf,
// ph3 B0(t+2)->curbuf (B-regions' last LDS read = ph2), ph4 A0(t+2)->curbuf
// (A-regions' last read = ph3) + vmcnt(4) which drains exactly through B1(t+1),
// the latest half-tile the next group's ph1 reads. Raw s_barrier (no vmcnt(0)
// drain) + asm memory fences.
#define BM2 256
#define BN2 256

template <int K, int N>
__global__ __launch_bounds__(512, 2) void k_bgemm2(
    const unsigned char* __restrict__ X, const unsigned char* __restrict__ W,
    short* __restrict__ A, ull* __restrict__ S, int M)
{
  __shared__ __align__(16) unsigned char lds[2][2][BM2 * 128];  // [buf][A=0/B=1]
  constexpr int Kb = K >> 1;
  constexpr int NT = K / 256;
  constexpr int NBX = N / BN2;
  const int t512 = threadIdx.x;
  const int lane = t512 & 63;
  const int wave = t512 >> 6;
  const int wm = wave >> 2;            // 0..1
  const int wn = wave & 3;             // 0..3
  const int wg = blockIdx.x;
  const int bm = (wg / NBX) * BM2, bn = (wg % NBX) * BN2;

  const int srow = lane >> 3;
  const int ssl = (lane & 7) ^ (srow & 7);   // inverse source swizzle (lane-only)

  // global bases per (half, chunk); row = half*128 + chunk*64 + wave*8 + srow
  const unsigned char* gA[2][2];
  const unsigned char* gB[2][2];
  int ldst[2][2];
#pragma unroll
  for (int h = 0; h < 2; ++h)
#pragma unroll
    for (int c = 0; c < 2; ++c) {
      int row = h * 128 + c * 64 + wave * 8 + srow;
      gA[h][c] = X + (size_t)(bm + row) * Kb + ssl * 16;
      gB[h][c] = W + (size_t)(bn + row) * Kb + ssl * 16;
      ldst[h][c] = (h * 128 + c * 64 + wave * 8) * 128;   // linear LDS dest
    }

  auto stageA = [&](int h, int buf, int tt) {
    GLOAD16(gA[h][0] + tt * 128, &lds[buf][0][ldst[h][0]]);
    GLOAD16(gA[h][1] + tt * 128, &lds[buf][0][ldst[h][1]]);
  };
  auto stageB = [&](int h, int buf, int tt) {
    GLOAD16(gB[h][0] + tt * 128, &lds[buf][1][ldst[h][0]]);
    GLOAD16(gB[h][1] + tt * 128, &lds[buf][1][ldst[h][1]]);
  };

  // ds_read offsets (swizzled)
  int aoff[8], boff[4];
#pragma unroll
  for (int m = 0; m < 8; ++m) {
    int r = wm * 128 + m * 16 + (lane & 15);
    aoff[m] = r * 128 + (((lane >> 4) ^ (r & 7)) * 16);
  }
#pragma unroll
  for (int n = 0; n < 4; ++n) {
    int r = wn * 64 + n * 16 + (lane & 15);
    boff[n] = r * 128 + (((lane >> 4) ^ (r & 7)) * 16);
  }

  v4f acc[8][4] = {};
  v8i a8[4][2], b8[4][2];
#pragma unroll
  for (int i = 0; i < 4; ++i)
#pragma unroll
    for (int kk = 0; kk < 2; ++kk) { a8[i][kk] = (v8i)(0); b8[i][kk] = (v8i)(0); }

#define RD_A(mh, Ap)                                                           \
  _Pragma("unroll") for (int mq = 0; mq < 4; ++mq)                             \
    _Pragma("unroll") for (int kk = 0; kk < 2; ++kk) {                         \
      v4i tmp = *(const v4i*)((Ap) + (aoff[(mh) * 4 + mq] ^ (kk << 6)));       \
      a8[mq][kk][0] = tmp[0]; a8[mq][kk][1] = tmp[1];                          \
      a8[mq][kk][2] = tmp[2]; a8[mq][kk][3] = tmp[3]; }
#define RD_B(nh, Bp)                                                           \
  _Pragma("unroll") for (int nq = 0; nq < 2; ++nq)                             \
    _Pragma("unroll") for (int kk = 0; kk < 2; ++kk) {                         \
      v4i tmp = *(const v4i*)((Bp) + (boff[(nh) * 2 + nq] ^ (kk << 6)));       \
      b8[(nh) * 2 + nq][kk][0] = tmp[0]; b8[(nh) * 2 + nq][kk][1] = tmp[1];    \
      b8[(nh) * 2 + nq][kk][2] = tmp[2]; b8[(nh) * 2 + nq][kk][3] = tmp[3]; }
#define QUAD(mh, nh)                                                           \
  { __builtin_amdgcn_s_setprio(1);                                             \
    _Pragma("unroll") for (int mq = 0; mq < 4; ++mq)                           \
      _Pragma("unroll") for (int nq = 0; nq < 2; ++nq)                         \
        _Pragma("unroll") for (int kk = 0; kk < 2; ++kk)                       \
          acc[(mh) * 4 + mq][(nh) * 2 + nq] =                                  \
              __builtin_amdgcn_mfma_scale_f32_16x16x128_f8f6f4(                \
                  a8[mq][kk], b8[(nh) * 2 + nq][kk],                           \
                  acc[(mh) * 4 + mq][(nh) * 2 + nq],                           \
                  4, 4, 0, 0x7F7F7F7Fu, 0, 0x7F7F7F7Fu);                       \
    __builtin_amdgcn_s_setprio(0); }

  // prologue: t0 fully (8 loads), then t1's B0,A0 (4) -> vmcnt(4) drains t0
  stageA(0, 0, 0); stageB(0, 0, 0); stageA(1, 0, 0); stageB(1, 0, 0);
  stageB(0, 1, 1); stageA(0, 1, 1);
  asm volatile("s_waitcnt vmcnt(4)" ::: "memory");
  bar();

#pragma unroll 2
  for (int t = 0; t < NT; ++t) {
    const int p = t & 1, q = p ^ 1;
    const unsigned char* Ap = &lds[p][0][0];
    const unsigned char* Bp = &lds[p][1][0];
    // phase 1: (m0..3, n0..1)
    RD_A(0, Ap); RD_B(0, Bp);
    if (t + 1 < NT) stageA(1, q, t + 1);
    bar(); QUAD(0, 0); bar();
    // phase 2: (m0..3, n2..3)
    RD_B(1, Bp);
    if (t + 1 < NT) stageB(1, q, t + 1);
    bar(); QUAD(0, 1); bar();
    // phase 3: (m4..7, n0..1)
    RD_A(1, Ap);
    if (t + 2 < NT) stageB(0, p, t + 2);
    bar(); QUAD(1, 0); bar();
    // phase 4: (m4..7, n2..3)
    if (t + 2 < NT) {
      stageA(0, p, t + 2);
      asm volatile("s_waitcnt vmcnt(4)" ::: "memory");
    } else {
      asm volatile("s_waitcnt vmcnt(0)" ::: "memory");
    }
    bar(); QUAD(1, 1); bar();
  }
#undef RD_A
#undef RD_B
#undef QUAD

  // C layout (verified): col = lane&15, row = (lane>>4)*4 + reg; nontemporal
#pragma unroll
  for (int m = 0; m < 8; ++m) {
    int rbase = bm + wm * 128 + m * 16 + (lane >> 4) * 4;
#pragma unroll
    for (int n = 0; n < 4; ++n) {
      int col = bn + wn * 64 + n * 16 + (lane & 15);
#pragma unroll
      for (int r = 0; r < 4; ++r)
        __builtin_nontemporal_store((short)(int)acc[m][n][r],
                                    A + (size_t)(rbase + r) * N + col);
    }
  }

  // fused per-column stats (exact; sumsq widened to 64-bit: 128*4096^2 = 2^31)
#pragma unroll
  for (int n = 0; n < 4; ++n) {
    int s = 0; long long q64 = 0;
#pragma unroll
    for (int m = 0; m < 8; ++m) {
      int qq = 0;
#pragma unroll
      for (int r = 0; r < 4; ++r) {
        int v = (int)acc[m][n][r];
        s += v; qq += v * v;
      }
      q64 += qq;
    }
    s += __shfl_xor(s, 16); s += __shfl_xor(s, 32);
    q64 += __shfl_xor(q64, 16); q64 += __shfl_xor(q64, 32);
    if ((lane >> 4) == 0) {
      int col = bn + wn * 64 + n * 16 + (lane & 15);
      atomicAdd(&S[col], (ull)(long long)s);
      atomicAdd(&S[(size_t)N + col], (ull)q64);
    }
  }
}

// ---------------- 128x128 2-barrier kernel (kept for the small N=256 layer) ----
#define BM 128
#define BN 128

template <int K, int N>
__global__ __launch_bounds__(256, 2) void k_bgemm(
    const unsigned char* __restrict__ X, const unsigned char* __restrict__ W,
    short* __restrict__ A, ull* __restrict__ S, int M)
{
  __shared__ __align__(16) unsigned char As[BM * 128];
  __shared__ __align__(16) unsigned char Bs[BN * 128];
  constexpr int Kb = K >> 1;
  constexpr int NT = K / 256;
  constexpr int NBX = N / BN;
  const int t = threadIdx.x;
  const int lane = t & 63;
  const int wave = t >> 6;
  const int wm = wave >> 1, wn = wave & 1;
  const int wg = blockIdx.x;
  const int bm = (wg / NBX) * BM, bn = (wg % NBX) * BN;

  const int srow = lane >> 3;
  const int sslot = (lane & 7);

  const unsigned char* Xb0 = X + (size_t)bm * Kb;
  const unsigned char* Wb0 = W + (size_t)bn * Kb;

  v4f acc[4][4] = {};
  v8i a8[4], b8[4];
#pragma unroll
  for (int m = 0; m < 4; ++m) { a8[m] = (v8i)(0); b8[m] = (v8i)(0); }

  const unsigned char* gx[4];
  const unsigned char* gw[4];
  int ldsoff[4];
#pragma unroll
  for (int c = 0; c < 4; ++c) {
    int br = (wave * 4 + c) * 8;
    int row = br + srow;
    int ss = sslot ^ (row & 7);
    gx[c] = Xb0 + (size_t)row * Kb + ss * 16;
    gw[c] = Wb0 + (size_t)row * Kb + ss * 16;
    ldsoff[c] = br * 128;
  }
  int aoff[4], boff[4];
#pragma unroll
  for (int m = 0; m < 4; ++m) {
    int arow = wm * 64 + m * 16 + (lane & 15);
    aoff[m] = arow * 128 + (((lane >> 4) ^ (arow & 7)) * 16);
    int brow = wn * 64 + m * 16 + (lane & 15);
    boff[m] = brow * 128 + (((lane >> 4) ^ (brow & 7)) * 16);
  }

#pragma unroll
  for (int tile = 0; tile < NT; ++tile) {
#pragma unroll
    for (int c = 0; c < 4; ++c) {
      GLOAD16(gx[c] + tile * 128, As + ldsoff[c]);
      GLOAD16(gw[c] + tile * 128, Bs + ldsoff[c]);
    }
    __syncthreads();
#pragma unroll
    for (int kk = 0; kk < 2; ++kk) {
#pragma unroll
      for (int m = 0; m < 4; ++m) {
        v4i tmp = *(const v4i*)(As + (aoff[m] ^ (kk << 6)));
        a8[m][0] = tmp[0]; a8[m][1] = tmp[1]; a8[m][2] = tmp[2]; a8[m][3] = tmp[3];
      }
#pragma unroll
      for (int n = 0; n < 4; ++n) {
        v4i tmp = *(const v4i*)(Bs + (boff[n] ^ (kk << 6)));
        b8[n][0] = tmp[0]; b8[n][1] = tmp[1]; b8[n][2] = tmp[2]; b8[n][3] = tmp[3];
      }
#pragma unroll
      for (int m = 0; m < 4; ++m)
#pragma unroll
        for (int n = 0; n < 4; ++n)
          acc[m][n] = __builtin_amdgcn_mfma_scale_f32_16x16x128_f8f6f4(
              a8[m], b8[n], acc[m][n], 4, 4, 0, 0x7F7F7F7Fu, 0, 0x7F7F7F7Fu);
    }
    __syncthreads();
  }

#pragma unroll
  for (int m = 0; m < 4; ++m) {
    int rbase = bm + wm * 64 + m * 16 + (lane >> 4) * 4;
#pragma unroll
    for (int n = 0; n < 4; ++n) {
      int col = bn + wn * 64 + n * 16 + (lane & 15);
#pragma unroll
      for (int r = 0; r < 4; ++r)
        __builtin_nontemporal_store((short)(int)acc[m][n][r],
                                    A + (size_t)(rbase + r) * N + col);
    }
  }

#pragma unroll
  for (int n = 0; n < 4; ++n) {
    int s = 0, q = 0;
#pragma unroll
    for (int m = 0; m < 4; ++m)
#pragma unroll
      for (int r = 0; r < 4; ++r) {
        int v = (int)acc[m][n][r];
        s += v; q += v * v;
      }
    s += __shfl_xor(s, 16); s += __shfl_xor(s, 32);
    q += __shfl_xor(q, 16); q += __shfl_xor(q, 32);
    if ((lane >> 4) == 0) {
      int col = bn + wn * 64 + n * 16 + (lane & 15);
      atomicAdd(&S[col], (ull)(long long)s);
      atomicAdd(&S[(size_t)N + col], (ull)(long long)q);
    }
  }
}

// ---------------- stats -> (mean, g*rsqrt(var+eps)) per column ----------------
__global__ void k_finalize(const ull* __restrict__ sums, const float* __restrict__ g,
                           int M, int N, float* __restrict__ meanf, float* __restrict__ sgf) {
  int j = blockIdx.x * blockDim.x + threadIdx.x;
  if (j >= N) return;
  double sum = (double)(long long)sums[j];
  double sumsq = (double)(long long)sums[N + j];
  double mean = sum / (double)M;
  double var = sumsq / (double)M - mean * mean;
  if (var < 0.0) var = 0.0;
  double inv = 1.0 / sqrt(var + 1e-5);
  meanf[j] = (float)mean;
  sgf[j] = (float)(inv * (double)g[j]);
}

// ---------------- sign(batchnorm(a)) -> packed fp4 (bias cancels under BN) ----
__global__ void k_signbn_pack(const short* __restrict__ A, const float* __restrict__ meanf,
                              const float* __restrict__ sgf, const float* __restrict__ be,
                              uint* __restrict__ Xp, int total8, int nmask) {
  int i = blockIdx.x * blockDim.x + threadIdx.x;
  int stride = gridDim.x * blockDim.x;
  for (; i < total8; i += stride) {
    v8s a = __builtin_nontemporal_load((const v8s*)(A + (size_t)i * 8));
    int c0 = (i * 8) & nmask;
    uint b = 0;
#pragma unroll
    for (int j = 0; j < 8; ++j) {
      float z = ((float)a[j] - meanf[c0 + j]) * sgf[c0 + j] + be[c0 + j];
      b |= nib(z) << (4 * j);
    }
    Xp[i] = b;
  }
}

// ---------------- sign(batchnorm(a)) -> i8 (for the tail) ----------------
__global__ void k_signbn(const short4* __restrict__ A4, const float* __restrict__ meanf,
                         const float* __restrict__ sgf, const float* __restrict__ be,
                         char4* __restrict__ X4, int total4, int nmask) {
  int i = blockIdx.x * blockDim.x + threadIdx.x;
  int stride = gridDim.x * blockDim.x;
  for (; i < total4; i += stride) {
    short4 a = A4[i];
    int c0 = (i * 4) & nmask;
    char4 o;
    o.x = sgnf(((float)a.x - meanf[c0    ]) * sgf[c0    ] + be[c0    ]);
    o.y = sgnf(((float)a.y - meanf[c0 + 1]) * sgf[c0 + 1] + be[c0 + 1]);
    o.z = sgnf(((float)a.z - meanf[c0 + 2]) * sgf[c0 + 2] + be[c0 + 2]);
    o.w = sgnf(((float)a.w - meanf[c0 + 3]) * sgf[c0 + 3] + be[c0 + 3]);
    X4[i] = o;
  }
}

// ---------------- fused layers 3,4,5: X3[M,256] -> A5[M,10] + stats ----------------
__global__ __launch_bounds__(256) void k_tail(
    const signed char* __restrict__ X3, const signed char* __restrict__ W3,
    const signed char* __restrict__ W4, const signed char* __restrict__ W5,
    const float* __restrict__ b3, const float* __restrict__ b4,
    int* __restrict__ A5, ull* __restrict__ sums5, int M)
{
  __shared__ __align__(16) signed char sW3[16 * 256];
  __shared__ __align__(16) signed char sW4[256];
  __shared__ __align__(16) signed char sW5[160];
  __shared__ __align__(16) signed char sX[16 * 256];
  __shared__ signed char sH[16][16];
  __shared__ int bsum[10], bsq[10];
  int t = threadIdx.x;
  int rowBlock = blockIdx.x * 16;
  ((int4*)sW3)[t] = ((const int4*)W3)[t];
  ((int4*)sX)[t] = ((const int4*)(X3 + (size_t)rowBlock * 256))[t];
  if (t < 16) ((int4*)sW4)[t] = ((const int4*)W4)[t];
  if (t < 10) {
    ((int4*)sW5)[t] = ((const int4*)W5)[t];
    bsum[t] = 0; bsq[t] = 0;
  }
  __syncthreads();
  int r = t >> 4, j = t & 15;
  int d3 = 0;
#pragma unroll 8
  for (int k = 0; k < 256; ++k) d3 += (int)sX[r * 256 + k] * (int)sW3[j * 256 + k];
  sH[r][j] = sgnf((float)d3 + b3[j]);   // sign(hardtanh(z)) == sign(z)
  __syncthreads();
  int d4 = 0;
#pragma unroll
  for (int k = 0; k < 16; ++k) d4 += (int)sH[r][k] * (int)sW4[j * 16 + k];
  signed char x5 = sgnf((float)d4 + b4[j]);
  __syncthreads();
  sH[r][j] = x5;
  __syncthreads();
  if (j < 10) {
    int d5 = 0;
#pragma unroll
    for (int k = 0; k < 16; ++k) d5 += (int)sH[r][k] * (int)sW5[j * 16 + k];
    A5[(size_t)(rowBlock + r) * 10 + j] = d5;
    atomicAdd(&bsum[j], d5);
    atomicAdd(&bsq[j], d5 * d5);
  }
  __syncthreads();
  if (t < 10) {
    atomicAdd(&sums5[t], (ull)(long long)bsum[t]);
    atomicAdd(&sums5[10 + t], (ull)(long long)bsq[t]);
  }
}

// ---------------- final BN + log_softmax ----------------
__global__ void k_lsm(const int* __restrict__ A5, const float* __restrict__ meanf,
                      const float* __restrict__ sgf, const float* __restrict__ be,
                      float* __restrict__ out, int M) {
  int r = blockIdx.x * blockDim.x + threadIdx.x;
  if (r >= M) return;
  float tv[10]; float mx = -3.0e38f;
#pragma unroll
  for (int j = 0; j < 10; ++j) {
    tv[j] = ((float)A5[(size_t)r * 10 + j] - meanf[j]) * sgf[j] + be[j];
    mx = fmaxf(mx, tv[j]);
  }
  float s = 0.f;
#pragma unroll
  for (int j = 0; j < 10; ++j) s += expf(tv[j] - mx);
  float lse = mx + logf(s);
#pragma unroll
  for (int j = 0; j < 10; ++j) out[(size_t)r * 10 + j] = tv[j] - lse;
}

extern "C" void kernel_launch(void* const* d_in, const int* in_sizes, int n_in,
                              void* d_out, int out_size, void* d_ws, size_t ws_size,
                              hipStream_t stream) {
  const float* x   = (const float*)d_in[0];
  const float* w0f = (const float*)d_in[1];
  const float* w1f = (const float*)d_in[3];
  const float* w2f = (const float*)d_in[5];
  const float* w3f = (const float*)d_in[7];  const float* b3f = (const float*)d_in[8];
  const float* w4f = (const float*)d_in[9];  const float* b4f = (const float*)d_in[10];
  const float* w5f = (const float*)d_in[11];
  const float* g0 = (const float*)d_in[13]; const float* be0 = (const float*)d_in[14];
  const float* g1 = (const float*)d_in[15]; const float* be1 = (const float*)d_in[16];
  const float* g2 = (const float*)d_in[17]; const float* be2 = (const float*)d_in[18];
  const float* g3 = (const float*)d_in[19]; const float* be3 = (const float*)d_in[20];

  const int M = in_sizes[0] / 3072;   // 16384
  char* w = (char*)d_ws;
  short* Abuf          = (short*)w;                          // 134217728
  unsigned char* X0p   = (unsigned char*)(w + 134217728);    // packed fp4
  unsigned char* Xbp   = (unsigned char*)(w + 184549376);    // packed fp4
  signed char* X3      = (signed char*)(w + 251658240);      // i8
  unsigned char* Ws0p  = (unsigned char*)(w + 255852544);
  unsigned char* Ws1p  = (unsigned char*)(w + 268435456);
  unsigned char* Ws2p  = (unsigned char*)(w + 285212672);
  signed char* Ws3 = (signed char*)(w + 286261248);
  signed char* Ws4 = (signed char*)(w + 286265344);
  signed char* Ws5 = (signed char*)(w + 286265600);
  int* A5          = (int*)(w + 286265856);
  ull* S0          = (ull*)(w + 286921216);
  ull* S1          = (ull*)(w + 286986752);
  ull* S2          = (ull*)(w + 287052288);
  ull* S5          = (ull*)(w + 287056384);
  float* P0m = (float*)(w + 287056640); float* P0s = (float*)(w + 287073024);
  float* P1m = (float*)(w + 287089408); float* P1s = (float*)(w + 287105792);
  float* P2m = (float*)(w + 287122176); float* P2s = (float*)(w + 287123200);
  float* P5m = (float*)(w + 287124224); float* P5s = (float*)(w + 287124288);

  hipMemsetAsync(w + 286921216, 0, 135424, stream);

  auto binp = [&](const float* src, unsigned char* dst, int n) {
    int n8 = n / 8;
    int grid = (n8 + 255) / 256; if (grid > 8192) grid = 8192;
    k_binp<<<grid, 256, 0, stream>>>((const float4*)src, (uint*)dst, n8);
  };
  binp(x,   X0p,  M * 3072);
  binp(w0f, Ws0p, 4096 * 3072);
  binp(w1f, Ws1p, 4096 * 4096);
  binp(w2f, Ws2p, 256 * 4096);
  k_bin<<<1, 64, 0, stream>>>((const float4*)w3f, (char4*)Ws3, 16 * 256 / 4);
  k_bin<<<1, 64, 0, stream>>>((const float4*)w4f, (char4*)Ws4, 16 * 16 / 4);
  k_bin<<<1, 40, 0, stream>>>((const float4*)w5f, (char4*)Ws5, 10 * 16 / 4);

  // Layer 0: [M,3072] x [4096,3072]^T  (stats fused into GEMM epilogue)
  k_bgemm2<3072, 4096><<<(4096 / BN2) * (M / BM2), 512, 0, stream>>>(X0p, Ws0p, Abuf, S0, M);
  k_finalize<<<16, 256, 0, stream>>>(S0, g0, M, 4096, P0m, P0s);
  k_signbn_pack<<<8192, 256, 0, stream>>>(Abuf, P0m, P0s, be0, (uint*)Xbp, M * 4096 / 8, 4095);

  // Layer 1: [M,4096] x [4096,4096]^T
  k_bgemm2<4096, 4096><<<(4096 / BN2) * (M / BM2), 512, 0, stream>>>(Xbp, Ws1p, Abuf, S1, M);
  k_finalize<<<16, 256, 0, stream>>>(S1, g1, M, 4096, P1m, P1s);
  k_signbn_pack<<<8192, 256, 0, stream>>>(Abuf, P1m, P1s, be1, (uint*)Xbp, M * 4096 / 8, 4095);

  // Layer 2: [M,4096] x [256,4096]^T  (small-N: keep 128^2 kernel, grid 256)
  k_bgemm<4096, 256><<<(256 / BN) * (M / BM), 256, 0, stream>>>(Xbp, Ws2p, Abuf, S2, M);
  k_finalize<<<1, 256, 0, stream>>>(S2, g2, M, 256, P2m, P2s);
  k_signbn<<<4096, 256, 0, stream>>>((const short4*)Abuf, P2m, P2s, be2, (char4*)X3, M * 256 / 4, 255);

  // Layers 3-5 fused + L5 stats
  k_tail<<<M / 16, 256, 0, stream>>>(X3, Ws3, Ws4, Ws5, b3f, b4f, A5, S5, M);
  k_finalize<<<1, 32, 0, stream>>>(S5, g3, M, 10, P5m, P5s);
  k_lsm<<<(M + 255) / 256, 256, 0, stream>>>(A5, P5m, P5s, be3, (float*)d_out, M);

  (void)n_in; (void)out_size; (void)ws_size;
}

// Round 8
// 502.118 us; speedup vs baseline: 3.3867x; 3.3867x over previous
//
#include <hip/hip_runtime.h>
#include <stdint.h>

typedef int v4i __attribute__((ext_vector_type(4)));
typedef int v8i __attribute__((ext_vector_type(8)));
typedef float v16f __attribute__((ext_vector_type(16)));
typedef short v8s __attribute__((ext_vector_type(8)));
typedef unsigned long long ull;
typedef unsigned int uint;

#define GLOAD16(g, l)                                                          \
  __builtin_amdgcn_global_load_lds(                                            \
      (const __attribute__((address_space(1))) void*)(g),                      \
      (__attribute__((address_space(3))) void*)(l), 16, 0, 0)

__device__ __forceinline__ signed char sgnf(float v) {
  return v > 0.f ? (signed char)1 : (v < 0.f ? (signed char)-1 : (signed char)0);
}
// fp4 e2m1 codes: +1.0 = 0x2, -1.0 = 0xA, 0.0 = 0x0
__device__ __forceinline__ uint nib(float v) {
  return v > 0.f ? 2u : (v < 0.f ? 10u : 0u);
}

// ---------------- binarize fp32 -> i8 sign (tiny weights only) ----------------
__global__ void k_bin(const float4* __restrict__ in, char4* __restrict__ out, int n4) {
  int i = blockIdx.x * blockDim.x + threadIdx.x;
  int stride = gridDim.x * blockDim.x;
  for (; i < n4; i += stride) {
    float4 v = in[i];
    char4 o;
    o.x = sgnf(v.x); o.y = sgnf(v.y); o.z = sgnf(v.z); o.w = sgnf(v.w);
    out[i] = o;
  }
}

// ---------------- binarize fp32 -> packed fp4 (2 elems/byte) ----------------
__global__ void k_binp(const float4* __restrict__ in, uint* __restrict__ out, int n8) {
  int i = blockIdx.x * blockDim.x + threadIdx.x;
  int stride = gridDim.x * blockDim.x;
  for (; i < n8; i += stride) {
    float4 a = in[i * 2], b = in[i * 2 + 1];
    out[i] = nib(a.x) | (nib(a.y) << 4) | (nib(a.z) << 8) | (nib(a.w) << 12) |
             (nib(b.x) << 16) | (nib(b.y) << 20) | (nib(b.z) << 24) | (nib(b.w) << 28);
  }
}

// ---- MX-fp4 binary GEMM, 32x32x64 shape: A[M,N] = X[M,K] * W[N,K]^T + stats ----
// R6-verified 2-barrier structure, single-buffer 32KB LDS, full unroll,
// natural block order (R5 lesson), nt stores. Shape switched to
// mfma_scale_f32_32x32x64_f8f6f4 (measured ceiling 9099 vs 7228 TF for 16x16).
// Per wave: 64x64 tile = 2x2 MFMAs per 64-elem K-subtile; 4 subtiles/K-tile.
// A/B frag: row = lane&31, 16B-half by lane>>5. C/D (verified m74/m101):
// col = lane&31, row = (reg&3) + 8*(reg>>2) + 4*(lane>>5).
#define BM 128
#define BN 128

template <int K, int N>
__global__ __launch_bounds__(256, 2) void k_bgemm(
    const unsigned char* __restrict__ X, const unsigned char* __restrict__ W,
    short* __restrict__ A, ull* __restrict__ S, int M)
{
  __shared__ __align__(16) unsigned char As[BM * 128];
  __shared__ __align__(16) unsigned char Bs[BN * 128];
  constexpr int Kb = K >> 1;             // packed row stride in bytes
  constexpr int NT = K / 256;            // 256 elements (128 B) per K-tile
  constexpr int NBX = N / BN;
  const int t = threadIdx.x;
  const int lane = t & 63;
  const int wave = t >> 6;
  const int wm = wave >> 1, wn = wave & 1;
  const int wg = blockIdx.x;             // natural order (R5: %8 partitions W)
  const int bm = (wg / NBX) * BM, bn = (wg % NBX) * BN;

  const int srow = lane >> 3;
  const int sslot = (lane & 7);
  const int khalf = lane >> 5;           // 16B half of the 32B per-row K-subtile

  const unsigned char* Xb0 = X + (size_t)bm * Kb;
  const unsigned char* Wb0 = W + (size_t)bn * Kb;

  v16f acc[2][2] = {};
  v8i a8[2], b8[2];
#pragma unroll
  for (int i = 0; i < 2; ++i) { a8[i] = (v8i)(0); b8[i] = (v8i)(0); }

  // staging addresses (loop-invariant; tile offset folds into imm)
  const unsigned char* gx[4];
  const unsigned char* gw[4];
  int ldsoff[4];
#pragma unroll
  for (int c = 0; c < 4; ++c) {
    int br = (wave * 4 + c) * 8;
    int row = br + srow;
    int ss = sslot ^ (row & 7);          // inverse swizzle on SOURCE
    gx[c] = Xb0 + (size_t)row * Kb + ss * 16;
    gw[c] = Wb0 + (size_t)row * Kb + ss * 16;
    ldsoff[c] = br * 128;
  }

  // ds_read geometry: row base + per-(ksub) swizzled slot
  int abase[2], am[2], bbase[2], bmsk[2];
#pragma unroll
  for (int mb = 0; mb < 2; ++mb) {
    int arow = wm * 64 + mb * 32 + (lane & 31);
    abase[mb] = arow * 128; am[mb] = arow & 7;
    int brow = wn * 64 + mb * 32 + (lane & 31);
    bbase[mb] = brow * 128; bmsk[mb] = brow & 7;
  }

#pragma unroll
  for (int tile = 0; tile < NT; ++tile) {
#pragma unroll
    for (int c = 0; c < 4; ++c) {
      GLOAD16(gx[c] + tile * 128, As + ldsoff[c]);
      GLOAD16(gw[c] + tile * 128, Bs + ldsoff[c]);
    }
    __syncthreads();                     // drains vmcnt + barrier
#pragma unroll
    for (int ks = 0; ks < 4; ++ks) {     // 64-elem (32B/row) K-subtile
#pragma unroll
      for (int mb = 0; mb < 2; ++mb) {
        int slot = ((ks << 1) | khalf) ^ am[mb];
        v4i tmp = *(const v4i*)(As + abase[mb] + slot * 16);
        a8[mb][0] = tmp[0]; a8[mb][1] = tmp[1]; a8[mb][2] = tmp[2]; a8[mb][3] = tmp[3];
      }
#pragma unroll
      for (int nb = 0; nb < 2; ++nb) {
        int slot = ((ks << 1) | khalf) ^ bmsk[nb];
        v4i tmp = *(const v4i*)(Bs + bbase[nb] + slot * 16);
        b8[nb][0] = tmp[0]; b8[nb][1] = tmp[1]; b8[nb][2] = tmp[2]; b8[nb][3] = tmp[3];
      }
#pragma unroll
      for (int mb = 0; mb < 2; ++mb)
#pragma unroll
        for (int nb = 0; nb < 2; ++nb)
          acc[mb][nb] = __builtin_amdgcn_mfma_scale_f32_32x32x64_f8f6f4(
              a8[mb], b8[nb], acc[mb][nb], 4 /*fp4*/, 4 /*fp4*/,
              0, 0x7F7F7F7Fu, 0, 0x7F7F7F7Fu);
    }
    __syncthreads();                     // compute done before next overwrite
  }

  // C layout (verified): col = lane&31, row = (reg&3)+8*(reg>>2)+4*khalf; nt stores
#pragma unroll
  for (int mb = 0; mb < 2; ++mb) {
    int rbase = bm + wm * 64 + mb * 32 + 4 * khalf;
#pragma unroll
    for (int nb = 0; nb < 2; ++nb) {
      int col = bn + wn * 64 + nb * 32 + (lane & 31);
#pragma unroll
      for (int r = 0; r < 16; ++r) {
        int row = rbase + (r & 3) + 8 * (r >> 2);
        __builtin_nontemporal_store((short)(int)acc[mb][nb][r],
                                    A + (size_t)row * N + col);
      }
    }
  }

  // fused per-column stats (exact ints; deterministic integer atomics)
#pragma unroll
  for (int nb = 0; nb < 2; ++nb) {
    int s = 0, q = 0;
#pragma unroll
    for (int mb = 0; mb < 2; ++mb)
#pragma unroll
      for (int r = 0; r < 16; ++r) {
        int v = (int)acc[mb][nb][r];
        s += v; q += v * v;
      }
    s += __shfl_xor(s, 32);
    q += __shfl_xor(q, 32);
    if (khalf == 0) {
      int col = bn + wn * 64 + nb * 32 + (lane & 31);
      atomicAdd(&S[col], (ull)(long long)s);
      atomicAdd(&S[(size_t)N + col], (ull)(long long)q);
    }
  }
}

// ---------------- stats -> (mean, g*rsqrt(var+eps)) per column ----------------
__global__ void k_finalize(const ull* __restrict__ sums, const float* __restrict__ g,
                           int M, int N, float* __restrict__ meanf, float* __restrict__ sgf) {
  int j = blockIdx.x * blockDim.x + threadIdx.x;
  if (j >= N) return;
  double sum = (double)(long long)sums[j];
  double sumsq = (double)(long long)sums[N + j];
  double mean = sum / (double)M;
  double var = sumsq / (double)M - mean * mean;
  if (var < 0.0) var = 0.0;
  double inv = 1.0 / sqrt(var + 1e-5);
  meanf[j] = (float)mean;
  sgf[j] = (float)(inv * (double)g[j]);
}

// ---------------- sign(batchnorm(a)) -> packed fp4 (bias cancels under BN) ----
__global__ void k_signbn_pack(const short* __restrict__ A, const float* __restrict__ meanf,
                              const float* __restrict__ sgf, const float* __restrict__ be,
                              uint* __restrict__ Xp, int total8, int nmask) {
  int i = blockIdx.x * blockDim.x + threadIdx.x;
  int stride = gridDim.x * blockDim.x;
  for (; i < total8; i += stride) {
    v8s a = __builtin_nontemporal_load((const v8s*)(A + (size_t)i * 8));
    int c0 = (i * 8) & nmask;
    uint b = 0;
#pragma unroll
    for (int j = 0; j < 8; ++j) {
      float z = ((float)a[j] - meanf[c0 + j]) * sgf[c0 + j] + be[c0 + j];
      b |= nib(z) << (4 * j);
    }
    Xp[i] = b;
  }
}

// ---------------- sign(batchnorm(a)) -> i8 (for the tail) ----------------
__global__ void k_signbn(const short4* __restrict__ A4, const float* __restrict__ meanf,
                         const float* __restrict__ sgf, const float* __restrict__ be,
                         char4* __restrict__ X4, int total4, int nmask) {
  int i = blockIdx.x * blockDim.x + threadIdx.x;
  int stride = gridDim.x * blockDim.x;
  for (; i < total4; i += stride) {
    short4 a = A4[i];
    int c0 = (i * 4) & nmask;
    char4 o;
    o.x = sgnf(((float)a.x - meanf[c0    ]) * sgf[c0    ] + be[c0    ]);
    o.y = sgnf(((float)a.y - meanf[c0 + 1]) * sgf[c0 + 1] + be[c0 + 1]);
    o.z = sgnf(((float)a.z - meanf[c0 + 2]) * sgf[c0 + 2] + be[c0 + 2]);
    o.w = sgnf(((float)a.w - meanf[c0 + 3]) * sgf[c0 + 3] + be[c0 + 3]);
    X4[i] = o;
  }
}

// ---------------- fused layers 3,4,5: X3[M,256] -> A5[M,10] + stats ----------------
__global__ __launch_bounds__(256) void k_tail(
    const signed char* __restrict__ X3, const signed char* __restrict__ W3,
    const signed char* __restrict__ W4, const signed char* __restrict__ W5,
    const float* __restrict__ b3, const float* __restrict__ b4,
    int* __restrict__ A5, ull* __restrict__ sums5, int M)
{
  __shared__ __align__(16) signed char sW3[16 * 256];
  __shared__ __align__(16) signed char sW4[256];
  __shared__ __align__(16) signed char sW5[160];
  __shared__ __align__(16) signed char sX[16 * 256];
  __shared__ signed char sH[16][16];
  __shared__ int bsum[10], bsq[10];
  int t = threadIdx.x;
  int rowBlock = blockIdx.x * 16;
  ((int4*)sW3)[t] = ((const int4*)W3)[t];
  ((int4*)sX)[t] = ((const int4*)(X3 + (size_t)rowBlock * 256))[t];
  if (t < 16) ((int4*)sW4)[t] = ((const int4*)W4)[t];
  if (t < 10) {
    ((int4*)sW5)[t] = ((const int4*)W5)[t];
    bsum[t] = 0; bsq[t] = 0;
  }
  __syncthreads();
  int r = t >> 4, j = t & 15;
  int d3 = 0;
#pragma unroll 8
  for (int k = 0; k < 256; ++k) d3 += (int)sX[r * 256 + k] * (int)sW3[j * 256 + k];
  sH[r][j] = sgnf((float)d3 + b3[j]);   // sign(hardtanh(z)) == sign(z)
  __syncthreads();
  int d4 = 0;
#pragma unroll
  for (int k = 0; k < 16; ++k) d4 += (int)sH[r][k] * (int)sW4[j * 16 + k];
  signed char x5 = sgnf((float)d4 + b4[j]);
  __syncthreads();
  sH[r][j] = x5;
  __syncthreads();
  if (j < 10) {
    int d5 = 0;
#pragma unroll
    for (int k = 0; k < 16; ++k) d5 += (int)sH[r][k] * (int)sW5[j * 16 + k];
    A5[(size_t)(rowBlock + r) * 10 + j] = d5;
    atomicAdd(&bsum[j], d5);
    atomicAdd(&bsq[j], d5 * d5);
  }
  __syncthreads();
  if (t < 10) {
    atomicAdd(&sums5[t], (ull)(long long)bsum[t]);
    atomicAdd(&sums5[10 + t], (ull)(long long)bsq[t]);
  }
}

// ---------------- final BN + log_softmax ----------------
__global__ void k_lsm(const int* __restrict__ A5, const float* __restrict__ meanf,
                      const float* __restrict__ sgf, const float* __restrict__ be,
                      float* __restrict__ out, int M) {
  int r = blockIdx.x * blockDim.x + threadIdx.x;
  if (r >= M) return;
  float tv[10]; float mx = -3.0e38f;
#pragma unroll
  for (int j = 0; j < 10; ++j) {
    tv[j] = ((float)A5[(size_t)r * 10 + j] - meanf[j]) * sgf[j] + be[j];
    mx = fmaxf(mx, tv[j]);
  }
  float s = 0.f;
#pragma unroll
  for (int j = 0; j < 10; ++j) s += expf(tv[j] - mx);
  float lse = mx + logf(s);
#pragma unroll
  for (int j = 0; j < 10; ++j) out[(size_t)r * 10 + j] = tv[j] - lse;
}

extern "C" void kernel_launch(void* const* d_in, const int* in_sizes, int n_in,
                              void* d_out, int out_size, void* d_ws, size_t ws_size,
                              hipStream_t stream) {
  const float* x   = (const float*)d_in[0];
  const float* w0f = (const float*)d_in[1];
  const float* w1f = (const float*)d_in[3];
  const float* w2f = (const float*)d_in[5];
  const float* w3f = (const float*)d_in[7];  const float* b3f = (const float*)d_in[8];
  const float* w4f = (const float*)d_in[9];  const float* b4f = (const float*)d_in[10];
  const float* w5f = (const float*)d_in[11];
  const float* g0 = (const float*)d_in[13]; const float* be0 = (const float*)d_in[14];
  const float* g1 = (const float*)d_in[15]; const float* be1 = (const float*)d_in[16];
  const float* g2 = (const float*)d_in[17]; const float* be2 = (const float*)d_in[18];
  const float* g3 = (const float*)d_in[19]; const float* be3 = (const float*)d_in[20];

  const int M = in_sizes[0] / 3072;   // 16384
  char* w = (char*)d_ws;
  short* Abuf          = (short*)w;                          // 134217728
  unsigned char* X0p   = (unsigned char*)(w + 134217728);    // packed fp4
  unsigned char* Xbp   = (unsigned char*)(w + 184549376);    // packed fp4
  signed char* X3      = (signed char*)(w + 251658240);      // i8
  unsigned char* Ws0p  = (unsigned char*)(w + 255852544);
  unsigned char* Ws1p  = (unsigned char*)(w + 268435456);
  unsigned char* Ws2p  = (unsigned char*)(w + 285212672);
  signed char* Ws3 = (signed char*)(w + 286261248);
  signed char* Ws4 = (signed char*)(w + 286265344);
  signed char* Ws5 = (signed char*)(w + 286265600);
  int* A5          = (int*)(w + 286265856);
  ull* S0          = (ull*)(w + 286921216);
  ull* S1          = (ull*)(w + 286986752);
  ull* S2          = (ull*)(w + 287052288);
  ull* S5          = (ull*)(w + 287056384);
  float* P0m = (float*)(w + 287056640); float* P0s = (float*)(w + 287073024);
  float* P1m = (float*)(w + 287089408); float* P1s = (float*)(w + 287105792);
  float* P2m = (float*)(w + 287122176); float* P2s = (float*)(w + 287123200);
  float* P5m = (float*)(w + 287124224); float* P5s = (float*)(w + 287124288);

  hipMemsetAsync(w + 286921216, 0, 135424, stream);

  auto binp = [&](const float* src, unsigned char* dst, int n) {
    int n8 = n / 8;
    int grid = (n8 + 255) / 256; if (grid > 8192) grid = 8192;
    k_binp<<<grid, 256, 0, stream>>>((const float4*)src, (uint*)dst, n8);
  };
  binp(x,   X0p,  M * 3072);
  binp(w0f, Ws0p, 4096 * 3072);
  binp(w1f, Ws1p, 4096 * 4096);
  binp(w2f, Ws2p, 256 * 4096);
  k_bin<<<1, 64, 0, stream>>>((const float4*)w3f, (char4*)Ws3, 16 * 256 / 4);
  k_bin<<<1, 64, 0, stream>>>((const float4*)w4f, (char4*)Ws4, 16 * 16 / 4);
  k_bin<<<1, 40, 0, stream>>>((const float4*)w5f, (char4*)Ws5, 10 * 16 / 4);

  // Layer 0: [M,3072] x [4096,3072]^T  (stats fused into GEMM epilogue)
  k_bgemm<3072, 4096><<<(4096 / BN) * (M / BM), 256, 0, stream>>>(X0p, Ws0p, Abuf, S0, M);
  k_finalize<<<16, 256, 0, stream>>>(S0, g0, M, 4096, P0m, P0s);
  k_signbn_pack<<<8192, 256, 0, stream>>>(Abuf, P0m, P0s, be0, (uint*)Xbp, M * 4096 / 8, 4095);

  // Layer 1: [M,4096] x [4096,4096]^T
  k_bgemm<4096, 4096><<<(4096 / BN) * (M / BM), 256, 0, stream>>>(Xbp, Ws1p, Abuf, S1, M);
  k_finalize<<<16, 256, 0, stream>>>(S1, g1, M, 4096, P1m, P1s);
  k_signbn_pack<<<8192, 256, 0, stream>>>(Abuf, P1m, P1s, be1, (uint*)Xbp, M * 4096 / 8, 4095);

  // Layer 2: [M,4096] x [256,4096]^T  (output X3 stays i8 for the tail)
  k_bgemm<4096, 256><<<(256 / BN) * (M / BM), 256, 0, stream>>>(Xbp, Ws2p, Abuf, S2, M);
  k_finalize<<<1, 256, 0, stream>>>(S2, g2, M, 256, P2m, P2s);
  k_signbn<<<4096, 256, 0, stream>>>((const short4*)Abuf, P2m, P2s, be2, (char4*)X3, M * 256 / 4, 255);

  // Layers 3-5 fused + L5 stats
  k_tail<<<M / 16, 256, 0, stream>>>(X3, Ws3, Ws4, Ws5, b3f, b4f, A5, S5, M);
  k_finalize<<<1, 32, 0, stream>>>(S5, g3, M, 10, P5m, P5s);
  k_lsm<<<(M + 255) / 256, 256, 0, stream>>>(A5, P5m, P5s, be3, (float*)d_out, M);

  (void)n_in; (void)out_size; (void)ws_size;
}